// Round 4
// baseline (3442.913 us; speedup 1.0000x reference)
//
#include <hip/hip_runtime.h>
#include <math.h>

// ---------------------------------------------------------------------------
// HyperGNN2D forward. All f32. Sizes: Nn=Nnet=50000, Ep=150000, Eg=400000.
// Round 3: compile-time-K register-tiled GEMM (float4 cols/thread, unrolled k,
// float4 x loads, LDS weights). out1/out2 were 140us each at 4% efficiency.
// ---------------------------------------------------------------------------

// ---------------- tiled GEMM: Y = act( ((x1|x2)@W)*rs + b ) -----------------
// ACT: 0=none 1=leaky(0.01) 2=tanh 3=sigmoid.  M % 4 == 0, K1 % 4 == 0, K2 % 4 == 0.
template <int ACT, int K1, int K2, int M>
__global__ void gemm_tiled(const float* __restrict__ X1,
                           const float* __restrict__ X2,
                           const float* __restrict__ rowscale,
                           const float* __restrict__ W,     // [K1+K2, M] row-major
                           const float* __restrict__ bias,  // [M] or null
                           float* __restrict__ Y, int N) {
    constexpr int K = K1 + K2;
    constexpr int MG = M / 4;
    constexpr int ROWS = 256 / MG;  // rows per block
    __shared__ float sW[K * M];
    for (int t = threadIdx.x; t < K * M; t += 256) sW[t] = W[t];
    __syncthreads();
    const float4* sW4 = (const float4*)sW;
    const int lane = threadIdx.x % MG;
    const int rsub = threadIdx.x / MG;
    if (rsub >= ROWS) return;
    const long long rstride = (long long)gridDim.x * ROWS;
    for (long long n = (long long)blockIdx.x * ROWS + rsub; n < N; n += rstride) {
        float4 acc = {0.f, 0.f, 0.f, 0.f};
        {
            const float4* x4 = (const float4*)(X1 + n * K1);
#pragma unroll
            for (int k4 = 0; k4 < K1 / 4; ++k4) {
                float4 xv = x4[k4];
                float4 w0 = sW4[(k4 * 4 + 0) * MG + lane];
                float4 w1 = sW4[(k4 * 4 + 1) * MG + lane];
                float4 w2 = sW4[(k4 * 4 + 2) * MG + lane];
                float4 w3 = sW4[(k4 * 4 + 3) * MG + lane];
                acc.x += xv.x * w0.x + xv.y * w1.x + xv.z * w2.x + xv.w * w3.x;
                acc.y += xv.x * w0.y + xv.y * w1.y + xv.z * w2.y + xv.w * w3.y;
                acc.z += xv.x * w0.z + xv.y * w1.z + xv.z * w2.z + xv.w * w3.z;
                acc.w += xv.x * w0.w + xv.y * w1.w + xv.z * w2.w + xv.w * w3.w;
            }
        }
        if (K2 > 0) {
            const float4* x4 = (const float4*)(X2 + n * K2);
#pragma unroll
            for (int k4 = 0; k4 < K2 / 4; ++k4) {
                float4 xv = x4[k4];
                float4 w0 = sW4[(K1 + k4 * 4 + 0) * MG + lane];
                float4 w1 = sW4[(K1 + k4 * 4 + 1) * MG + lane];
                float4 w2 = sW4[(K1 + k4 * 4 + 2) * MG + lane];
                float4 w3 = sW4[(K1 + k4 * 4 + 3) * MG + lane];
                acc.x += xv.x * w0.x + xv.y * w1.x + xv.z * w2.x + xv.w * w3.x;
                acc.y += xv.x * w0.y + xv.y * w1.y + xv.z * w2.y + xv.w * w3.y;
                acc.z += xv.x * w0.z + xv.y * w1.z + xv.z * w2.z + xv.w * w3.z;
                acc.w += xv.x * w0.w + xv.y * w1.w + xv.z * w2.w + xv.w * w3.w;
            }
        }
        if (rowscale) {
            float rs = rowscale[n];
            acc.x *= rs; acc.y *= rs; acc.z *= rs; acc.w *= rs;
        }
        if (bias) {
            float4 bv = *(const float4*)(bias + lane * 4);
            acc.x += bv.x; acc.y += bv.y; acc.z += bv.z; acc.w += bv.w;
        }
        if (ACT == 1) {
            acc.x = acc.x >= 0.f ? acc.x : 0.01f * acc.x;
            acc.y = acc.y >= 0.f ? acc.y : 0.01f * acc.y;
            acc.z = acc.z >= 0.f ? acc.z : 0.01f * acc.z;
            acc.w = acc.w >= 0.f ? acc.w : 0.01f * acc.w;
        } else if (ACT == 2) {
            acc.x = tanhf(acc.x); acc.y = tanhf(acc.y);
            acc.z = tanhf(acc.z); acc.w = tanhf(acc.w);
        } else if (ACT == 3) {
            acc.x = 1.f / (1.f + expf(-acc.x)); acc.y = 1.f / (1.f + expf(-acc.y));
            acc.z = 1.f / (1.f + expf(-acc.z)); acc.w = 1.f / (1.f + expf(-acc.w));
        }
        *(float4*)(Y + n * M + lane * 4) = acc;
    }
}

// ---------------- CSR build --------------------------------------------------
__global__ void count_int(const int* __restrict__ key, int* __restrict__ cnt, int E) {
    for (int e = blockIdx.x * blockDim.x + threadIdx.x; e < E; e += gridDim.x * blockDim.x)
        atomicAdd(&cnt[key[e]], 1);
}
__global__ void count_int2(const int* __restrict__ k1, const int* __restrict__ k2,
                           int* __restrict__ c1, int* __restrict__ c2, int E) {
    for (int e = blockIdx.x * blockDim.x + threadIdx.x; e < E; e += gridDim.x * blockDim.x) {
        atomicAdd(&c1[k1[e]], 1);
        atomicAdd(&c2[k2[e]], 1);
    }
}

// ---------------- device-wide 3-phase exclusive scan -------------------------
#define SCAN_T 256
#define SCAN_V 4
#define SCAN_CHUNK (SCAN_T * SCAN_V)

__global__ void scan_phase1(const int* __restrict__ cnt, int* __restrict__ out,
                            int* __restrict__ partials, int N) {
    __shared__ int sdata[SCAN_T];
    const int b = blockIdx.x;
    const int base = b * SCAN_CHUNK;
    int v[SCAN_V];
    int s = 0;
#pragma unroll
    for (int k = 0; k < SCAN_V; ++k) {
        int i = base + threadIdx.x * SCAN_V + k;
        v[k] = (i < N) ? cnt[i] : 0;
        s += v[k];
    }
    sdata[threadIdx.x] = s;
    __syncthreads();
    for (int ofs = 1; ofs < SCAN_T; ofs <<= 1) {
        int t = (threadIdx.x >= ofs) ? sdata[threadIdx.x - ofs] : 0;
        __syncthreads();
        sdata[threadIdx.x] += t;
        __syncthreads();
    }
    int excl = sdata[threadIdx.x] - s;
#pragma unroll
    for (int k = 0; k < SCAN_V; ++k) {
        int i = base + threadIdx.x * SCAN_V + k;
        if (i < N) out[i] = excl;
        excl += v[k];
    }
    if (threadIdx.x == SCAN_T - 1) partials[b] = sdata[SCAN_T - 1];
}

__global__ void scan_phase2(int* __restrict__ partials, int nb) {
    __shared__ int sdata[SCAN_T];
    int v = (threadIdx.x < nb) ? partials[threadIdx.x] : 0;
    sdata[threadIdx.x] = v;
    __syncthreads();
    for (int ofs = 1; ofs < SCAN_T; ofs <<= 1) {
        int t = (threadIdx.x >= ofs) ? sdata[threadIdx.x - ofs] : 0;
        __syncthreads();
        sdata[threadIdx.x] += t;
        __syncthreads();
    }
    if (threadIdx.x < nb) partials[threadIdx.x] = sdata[threadIdx.x] - v;
    if (threadIdx.x == SCAN_T - 1) partials[nb] = sdata[SCAN_T - 1];
}

__global__ void scan_phase3(int* __restrict__ rowptr, const int* __restrict__ partials,
                            int N, int nb) {
    int i = blockIdx.x * blockDim.x + threadIdx.x;
    if (i < N) rowptr[i] += partials[i / SCAN_CHUNK];
    else if (i == N) rowptr[N] = partials[nb];
}

// adj[pos] = val ? val[e] : e
__global__ void fill_adj(const int* __restrict__ key, const int* __restrict__ val,
                         int* __restrict__ cursor, int* __restrict__ adj, int E) {
    for (int e = blockIdx.x * blockDim.x + threadIdx.x; e < E; e += gridDim.x * blockDim.x) {
        int pos = atomicAdd(&cursor[key[e]], 1);
        adj[pos] = val ? val[e] : e;
    }
}

__global__ void deg_xform(const int* __restrict__ cnt, float* __restrict__ rs,
                          float* __restrict__ inv, int N) {
    for (int n = blockIdx.x * blockDim.x + threadIdx.x; n < N; n += gridDim.x * blockDim.x) {
        float d = fmaxf((float)cnt[n], 1.f);
        rs[n] = 1.f / sqrtf(d);
        if (inv) inv[n] = 1.f / d;
    }
}

// ---------------- GAT -------------------------------------------------------
__global__ void gat_scores(const float* __restrict__ h, const float* __restrict__ al,
                           const float* __restrict__ ar, float* __restrict__ el,
                           float* __restrict__ er, int N) {
    int idx = blockIdx.x * blockDim.x + threadIdx.x;
    if (idx >= N * 4) return;
    int n = idx >> 2, hd = idx & 3;
    const float* hp = h + (long long)n * 32 + hd * 8;
    float sl = 0.f, sr = 0.f;
#pragma unroll
    for (int f = 0; f < 8; ++f) {
        float v = hp[f];
        sl += v * al[hd * 8 + f];
        sr += v * ar[hd * 8 + f];
    }
    el[idx] = sl;
    er[idx] = sr;
}

// one thread per (dst,head): max pass, then fused exp/sum/weighted-accumulate
__global__ void gat_gather(const int* __restrict__ rowptr, const int* __restrict__ adjsrc,
                           const float* __restrict__ el, const float* __restrict__ er,
                           const float* __restrict__ gh, float* __restrict__ out,
                           int colOff, int N) {
    int idx = blockIdx.x * blockDim.x + threadIdx.x;
    if (idx >= N * 4) return;
    int d = idx >> 2, hd = idx & 3;
    int beg = rowptr[d], end = rowptr[d + 1];
    float rd = er[d * 4 + hd];
    float m = -1e30f;
    for (int p = beg; p < end; ++p) {
        float v = el[adjsrc[p] * 4 + hd] + rd;
        v = v >= 0.f ? v : 0.2f * v;
        m = fmaxf(m, v);
    }
    if (end == beg) m = 0.f;
    float sum = 0.f;
    float acc[8] = {0.f, 0.f, 0.f, 0.f, 0.f, 0.f, 0.f, 0.f};
    for (int p = beg; p < end; ++p) {
        int s = adjsrc[p];
        float v = el[s * 4 + hd] + rd;
        v = v >= 0.f ? v : 0.2f * v;
        float w = expf(v - m);
        sum += w;
        const float* hp = gh + (long long)s * 32 + hd * 8;
#pragma unroll
        for (int f = 0; f < 8; ++f) acc[f] += w * hp[f];
    }
    float inv = 1.f / fmaxf(sum, 1e-9f);
    float* op = out + (long long)d * 96 + hd * 16 + colOff;
#pragma unroll
    for (int f = 0; f < 8; ++f) op[f] = acc[f] * inv;
}

// ---------------- GraphConv gather (net <- sum over incoming pins) ----------
__global__ void gconv_gather(const int* __restrict__ rowptr, const int* __restrict__ adj,
                             const float* __restrict__ h, float* __restrict__ out, int N) {
    long long total = (long long)N * 32;
    long long stride = (long long)gridDim.x * blockDim.x;
    for (long long idx = (long long)blockIdx.x * blockDim.x + threadIdx.x; idx < total; idx += stride) {
        int n = (int)(idx >> 5), c = (int)(idx & 31);
        int beg = rowptr[n], end = rowptr[n + 1];
        float acc = 0.f;
        for (int p = beg; p < end; ++p) acc += h[(long long)adj[p] * 32 + c];
        out[idx] = acc;
    }
}

// ---------------- NNConv edge GEMM -> msg buffer -----------------------------
#define NN_TILE 64
__launch_bounds__(256, 2)
__global__ void nnconv_kernel(const int* __restrict__ esrc,   // net idx per edge (pins_dst)
                              const float* __restrict__ net,  // [Nnet,32]
                              const float* __restrict__ pinf, // [Ep,16]
                              const float* __restrict__ w,    // [16*1024]
                              const float* __restrict__ b2,   // [1024]
                              float* __restrict__ msg,        // [Ep,32]
                              int E) {
    __shared__ float sw[16 * 1024];
    __shared__ float sxT[32][NN_TILE];
    for (int t = threadIdx.x; t < 16 * 1024; t += 256) sw[t] = w[t];
    const float4* sw4 = (const float4*)sw;
    float4* msg4 = (float4*)msg;
    const int o4 = threadIdx.x & 7;
    const int eg = threadIdx.x >> 3;
    const int le0 = eg * 2;
    const int o0 = o4 * 4;
    const int ntiles = (E + NN_TILE - 1) / NN_TILE;
    for (int tile = blockIdx.x; tile < ntiles; tile += gridDim.x) {
        const int e0 = tile * NN_TILE;
        __syncthreads();
        for (int t = threadIdx.x; t < NN_TILE * 32; t += 256) {
            int le = t >> 5, c = t & 31;
            int e = e0 + le;
            sxT[c][le] = (e < E) ? net[(long long)esrc[e] * 32 + c] : 0.f;
        }
        float P0[16], P1[16];
        {
            int ea = e0 + le0, eb = e0 + le0 + 1;
#pragma unroll
            for (int k = 0; k < 16; ++k) {
                P0[k] = (ea < E) ? pinf[(long long)ea * 16 + k] : 0.f;
                P1[k] = (eb < E) ? pinf[(long long)eb * 16 + k] : 0.f;
            }
        }
        __syncthreads();
        float4 acc0 = {0.f, 0.f, 0.f, 0.f}, acc1 = {0.f, 0.f, 0.f, 0.f};
        for (int i = 0; i < 32; ++i) {
            float x0 = sxT[i][le0];
            float x1 = sxT[i][le0 + 1];
            float4 bv = *(const float4*)(b2 + i * 32 + o0);
            acc0.x += bv.x * x0; acc0.y += bv.y * x0; acc0.z += bv.z * x0; acc0.w += bv.w * x0;
            acc1.x += bv.x * x1; acc1.y += bv.y * x1; acc1.z += bv.z * x1; acc1.w += bv.w * x1;
#pragma unroll
            for (int k = 0; k < 16; ++k) {
                float4 wv = sw4[k * 256 + i * 8 + o4];
                float s0 = x0 * P0[k];
                float s1 = x1 * P1[k];
                acc0.x += wv.x * s0; acc0.y += wv.y * s0; acc0.z += wv.z * s0; acc0.w += wv.w * s0;
                acc1.x += wv.x * s1; acc1.y += wv.y * s1; acc1.z += wv.z * s1; acc1.w += wv.w * s1;
            }
        }
        int ea = e0 + le0;
        if (ea < E) msg4[(long long)ea * 8 + o4] = acc0;
        if (ea + 1 < E) msg4[(long long)(ea + 1) * 8 + o4] = acc1;
    }
}

// gather msg by node (pins_src CSR stores edge ids)
__global__ void nn_gather(const int* __restrict__ rowptr, const int* __restrict__ adjE,
                          const float* __restrict__ msg, float* __restrict__ out, int N) {
    long long total = (long long)N * 32;
    long long stride = (long long)gridDim.x * blockDim.x;
    for (long long idx = (long long)blockIdx.x * blockDim.x + threadIdx.x; idx < total; idx += stride) {
        int n = (int)(idx >> 5), o = (int)(idx & 31);
        int beg = rowptr[n], end = rowptr[n + 1];
        float acc = 0.f;
        for (int p = beg; p < end; ++p) acc += msg[(long long)adjE[p] * 32 + o];
        out[(long long)n * 96 + 64 + o] = acc;
    }
}

// ---------------- finalizers -------------------------------------------------
__global__ void finalize_node(float* __restrict__ node, const float* __restrict__ invN,
                              const float* __restrict__ gbias, const float* __restrict__ nnb, int N) {
    long long total = (long long)N * 96;
    long long stride = (long long)gridDim.x * blockDim.x;
    for (long long idx = (long long)blockIdx.x * blockDim.x + threadIdx.x; idx < total; idx += stride) {
        int n = (int)(idx / 96), c = (int)(idx % 96);
        float v = node[idx];
        if (c < 64) v += gbias[((c >> 4) << 3) | (c & 7)];
        else v = v * invN[n] + nnb[c - 64];
        node[idx] = tanhf(v);
    }
}
__global__ void finalize_net(float* __restrict__ net, const float* __restrict__ rsNet,
                             const float* __restrict__ gb, int N) {
    long long total = (long long)N * 32;
    long long stride = (long long)gridDim.x * blockDim.x;
    for (long long idx = (long long)blockIdx.x * blockDim.x + threadIdx.x; idx < total; idx += stride) {
        int n = (int)(idx >> 5), c = (int)(idx & 31);
        net[idx] = tanhf(net[idx] * rsNet[n] + gb[c]);
    }
}

// ---------------------------------------------------------------------------
extern "C" void kernel_launch(void* const* d_in, const int* in_sizes, int n_in,
                              void* d_out, int out_size, void* d_ws, size_t ws_size,
                              hipStream_t stream) {
    const float* in_node = (const float*)d_in[0];
    const float* in_net = (const float*)d_in[1];
    const float* in_pinf = (const float*)d_in[2];
    const float* node_lin_w = (const float*)d_in[3];
    const float* node_lin_b = (const float*)d_in[4];
    const float* net_lin_w = (const float*)d_in[5];
    const float* net_lin_b = (const float*)d_in[6];
    const float* pin_lin_w = (const float*)d_in[7];
    const float* pin_lin_b = (const float*)d_in[8];
    const float* gat_fc_w = (const float*)d_in[9];
    const float* gat_attn_l = (const float*)d_in[10];
    const float* gat_attn_r = (const float*)d_in[11];
    const float* gat_bias = (const float*)d_in[12];
    const float* gconv_w = (const float*)d_in[13];
    const float* gconv_b = (const float*)d_in[14];
    const float* lin2_w = (const float*)d_in[15];
    const float* lin2_b = (const float*)d_in[16];
    const float* nnconv_bias = (const float*)d_in[17];
    const float* out1_w = (const float*)d_in[18];
    const float* out1_b = (const float*)d_in[19];
    const float* out2_w = (const float*)d_in[20];
    const float* out2_b = (const float*)d_in[21];
    const float* out3_w = (const float*)d_in[22];
    const float* out3_b = (const float*)d_in[23];
    const int* pins_src = (const int*)d_in[24];
    const int* pins_dst = (const int*)d_in[25];
    const int* grid_src = (const int*)d_in[26];
    const int* grid_dst = (const int*)d_in[27];

    const int Nn = in_sizes[0] / 16;
    const int Nnet = in_sizes[1] / 8;
    const int Ep = in_sizes[2] / 8;
    const int Eg = in_sizes[26] / 2;

    char* base = (char*)d_ws;
    size_t off = 0;
    auto alloc = [&](size_t bytes) -> void* {
        void* p = base + off;
        off += (bytes + 255) & ~(size_t)255;
        return p;
    };
    float* pin = (float*)alloc((size_t)Ep * 16 * 4);
    float* msg = (float*)alloc((size_t)Ep * 32 * 4);
    float* rsN = (float*)alloc((size_t)Nn * 4);
    float* invN = (float*)alloc((size_t)Nn * 4);
    float* rsNet = (float*)alloc((size_t)Nnet * 4);
    int* cntN = (int*)alloc((size_t)Nn * 4);
    int* cntNet = (int*)alloc((size_t)Nnet * 4);
    int* cntG = (int*)alloc((size_t)Nn * 4);
    int* cursor = (int*)alloc((size_t)(Nn > Nnet ? Nn : Nnet) * 4);
    int* partials = (int*)alloc((size_t)260 * 4);
    float* nodeA = (float*)alloc((size_t)Nn * 96 * 4);
    float* nodeB = (float*)alloc((size_t)Nn * 96 * 4);
    float* netA = (float*)alloc((size_t)Nnet * 32 * 4);
    float* netB = (float*)alloc((size_t)Nnet * 32 * 4);
    float* gat_h = (float*)alloc((size_t)Nn * 32 * 4);
    float* el = (float*)alloc((size_t)Nn * 4 * 4);
    float* er = (float*)alloc((size_t)Nn * 4 * 4);
    float* gconv_h = (float*)alloc((size_t)Nn * 32 * 4);
    int* gridPtr0 = (int*)alloc((size_t)(Nn + 1) * 4);
    int* gridPtr1 = (int*)alloc((size_t)(Nn + 1) * 4);
    int* gridAdj0 = (int*)alloc((size_t)Eg * 4);
    int* gridAdj1 = (int*)alloc((size_t)Eg * 4);
    int* pinDstPtr = (int*)alloc((size_t)(Nnet + 1) * 4);
    int* pinDstAdj = (int*)alloc((size_t)Ep * 4);
    int* pinSrcPtr = (int*)alloc((size_t)(Nn + 1) * 4);
    int* pinSrcAdjE = (int*)alloc((size_t)Ep * 4);

    auto gsz = [](long long total) -> int {
        long long b = (total + 255) / 256;
        if (b < 1) b = 1;
        if (b > 4096) b = 4096;
        return (int)b;
    };

    // device-wide exclusive scan: cnt[N] -> rowptr[N+1]
    auto exscan = [&](const int* cnt, int* rowptr, int N) {
        int nb = (N + SCAN_CHUNK - 1) / SCAN_CHUNK;
        scan_phase1<<<nb, SCAN_T, 0, stream>>>(cnt, rowptr, partials, N);
        scan_phase2<<<1, SCAN_T, 0, stream>>>(partials, nb);
        scan_phase3<<<(N + 256) / 256 + 1, 256, 0, stream>>>(rowptr, partials, N, nb);
    };

    // ---- degrees for pins ----
    hipMemsetAsync(cntN, 0, (size_t)Nn * 4, stream);
    hipMemsetAsync(cntNet, 0, (size_t)Nnet * 4, stream);
    count_int2<<<gsz(Ep), 256, 0, stream>>>(pins_src, pins_dst, cntN, cntNet, Ep);
    deg_xform<<<gsz(Nn), 256, 0, stream>>>(cntN, rsN, invN, Nn);
    deg_xform<<<gsz(Nnet), 256, 0, stream>>>(cntNet, rsNet, nullptr, Nnet);

    // ---- CSR: pins by dst (net <- node), adj stores src node ----
    exscan(cntNet, pinDstPtr, Nnet);
    hipMemcpyAsync(cursor, pinDstPtr, (size_t)Nnet * 4, hipMemcpyDeviceToDevice, stream);
    fill_adj<<<gsz(Ep), 256, 0, stream>>>(pins_dst, pins_src, cursor, pinDstAdj, Ep);

    // ---- CSR: pins by src (node <- msg edges), adj stores edge id ----
    exscan(cntN, pinSrcPtr, Nn);
    hipMemcpyAsync(cursor, pinSrcPtr, (size_t)Nn * 4, hipMemcpyDeviceToDevice, stream);
    fill_adj<<<gsz(Ep), 256, 0, stream>>>(pins_src, nullptr, cursor, pinSrcAdjE, Ep);

    // ---- CSR: grid channels by dst, adj stores src node ----
    {
        int* ptrs[2] = {gridPtr0, gridPtr1};
        int* adjs[2] = {gridAdj0, gridAdj1};
        for (int j = 0; j < 2; ++j) {
            const int* gs = grid_src + (size_t)j * Eg;
            const int* gd = grid_dst + (size_t)j * Eg;
            hipMemsetAsync(cntG, 0, (size_t)Nn * 4, stream);
            count_int<<<gsz(Eg), 256, 0, stream>>>(gd, cntG, Eg);
            exscan(cntG, ptrs[j], Nn);
            hipMemcpyAsync(cursor, ptrs[j], (size_t)Nn * 4, hipMemcpyDeviceToDevice, stream);
            fill_adj<<<gsz(Eg), 256, 0, stream>>>(gd, gs, cursor, adjs[j], Eg);
        }
    }

    // tiled-GEMM launch helper: blocks so that each covers ROWS rows
    auto blocks_for = [](int N, int M) -> int {
        int rows = 256 / (M / 4);
        long long b = ((long long)N + rows - 1) / rows;
        return (int)b;
    };

    // ---- input transforms ----
    gemm_tiled<1, 16, 0, 96><<<blocks_for(Nn, 96), 256, 0, stream>>>(
        in_node, nullptr, nullptr, node_lin_w, node_lin_b, nodeA, Nn);
    gemm_tiled<1, 8, 0, 32><<<blocks_for(Nnet, 32), 256, 0, stream>>>(
        in_net, nullptr, nullptr, net_lin_w, net_lin_b, netA, Nnet);
    gemm_tiled<1, 8, 0, 16><<<blocks_for(Ep, 16), 256, 0, stream>>>(
        in_pinf, nullptr, nullptr, pin_lin_w, pin_lin_b, pin, Ep);

    float* node_cur = nodeA; float* node_nxt = nodeB;
    float* net_cur = netA;  float* net_nxt = netB;

    for (int i = 0; i < 2; ++i) {
        // GAT shared projection + attention scores
        gemm_tiled<0, 96, 0, 32><<<blocks_for(Nn, 32), 256, 0, stream>>>(
            node_cur, nullptr, nullptr, gat_fc_w + (size_t)i * 96 * 32, nullptr, gat_h, Nn);
        gat_scores<<<(Nn * 4 + 255) / 256, 256, 0, stream>>>(
            gat_h, gat_attn_l + i * 32, gat_attn_r + i * 32, el, er, Nn);

        gat_gather<<<(Nn * 4 + 255) / 256, 256, 0, stream>>>(
            gridPtr0, gridAdj0, el, er, gat_h, node_nxt, 0, Nn);
        gat_gather<<<(Nn * 4 + 255) / 256, 256, 0, stream>>>(
            gridPtr1, gridAdj1, el, er, gat_h, node_nxt, 8, Nn);

        // GraphConv: h = (node * deg^-1/2) @ W; gather to nets
        gemm_tiled<0, 96, 0, 32><<<blocks_for(Nn, 32), 256, 0, stream>>>(
            node_cur, nullptr, rsN, gconv_w + (size_t)i * 96 * 32, nullptr, gconv_h, Nn);
        gconv_gather<<<gsz((long long)Nnet * 32), 256, 0, stream>>>(
            pinDstPtr, pinDstAdj, gconv_h, net_nxt, Nnet);

        // NNConv: per-edge weight matrices -> msg, then gather by node
        {
            int ntiles = (Ep + NN_TILE - 1) / NN_TILE;
            int g = ntiles < 512 ? ntiles : 512;
            nnconv_kernel<<<g, 256, 0, stream>>>(pins_dst, net_cur, pin,
                                                 lin2_w + (size_t)i * 16 * 1024,
                                                 lin2_b + (size_t)i * 1024, msg, Ep);
        }
        nn_gather<<<gsz((long long)Nn * 32), 256, 0, stream>>>(
            pinSrcPtr, pinSrcAdjE, msg, node_nxt, Nn);

        finalize_node<<<gsz((long long)Nn * 96), 256, 0, stream>>>(
            node_nxt, invN, gat_bias + i * 32, nnconv_bias + i * 32, Nn);
        finalize_net<<<gsz((long long)Nnet * 32), 256, 0, stream>>>(net_nxt, rsNet, gconv_b + i * 32, Nnet);

        float* t = node_cur; node_cur = node_nxt; node_nxt = t;
        t = net_cur; net_cur = net_nxt; net_nxt = t;
    }

    // output MLP
    float* h1 = node_nxt;
    gemm_tiled<2, 16, 96, 96><<<blocks_for(Nn, 96), 256, 0, stream>>>(
        in_node, node_cur, nullptr, out1_w, out1_b, h1, Nn);
    float* h2 = node_cur;
    gemm_tiled<2, 96, 0, 96><<<blocks_for(Nn, 96), 256, 0, stream>>>(
        h1, nullptr, nullptr, out2_w, out2_b, h2, Nn);
    gemm_tiled<3, 96, 0, 4><<<blocks_for(Nn, 4), 256, 0, stream>>>(
        h2, nullptr, nullptr, out3_w, out3_b, (float*)d_out, Nn);
}

// Round 5
// 712.391 us; speedup vs baseline: 4.8329x; 4.8329x over previous
//
#include <hip/hip_runtime.h>
#include <math.h>

// ---------------------------------------------------------------------------
// HyperGNN2D forward. All f32. Sizes: Nn=Nnet=50000, Ep=150000, Eg=400000.
// Round 4 fix: gemm_tiled's fully-unrolled k-loop spilled ~1.6KB/thread to
// scratch (2GB writes/dispatch, 949us). #pragma unroll 4 bounds live range;
// grid capped at 1280 blocks (grid-stride) to amortize LDS weight staging.
// ---------------------------------------------------------------------------

// ---------------- tiled GEMM: Y = act( ((x1|x2)@W)*rs + b ) -----------------
// ACT: 0=none 1=leaky(0.01) 2=tanh 3=sigmoid.  M % 4 == 0, K1 % 4 == 0, K2 % 4 == 0.
template <int ACT, int K1, int K2, int M>
__global__ void gemm_tiled(const float* __restrict__ X1,
                           const float* __restrict__ X2,
                           const float* __restrict__ rowscale,
                           const float* __restrict__ W,     // [K1+K2, M] row-major
                           const float* __restrict__ bias,  // [M] or null
                           float* __restrict__ Y, int N) {
    constexpr int K = K1 + K2;
    constexpr int MG = M / 4;
    constexpr int ROWS = 256 / MG;  // rows per block per tile
    __shared__ float sW[K * M];
    for (int t = threadIdx.x; t < K * M; t += 256) sW[t] = W[t];
    __syncthreads();
    const float4* sW4 = (const float4*)sW;
    const int lane = threadIdx.x % MG;
    const int rsub = threadIdx.x / MG;
    if (rsub >= ROWS) return;
    const long long rstride = (long long)gridDim.x * ROWS;
    for (long long n = (long long)blockIdx.x * ROWS + rsub; n < N; n += rstride) {
        float4 acc = {0.f, 0.f, 0.f, 0.f};
        {
            const float4* x4 = (const float4*)(X1 + n * K1);
#pragma unroll 4
            for (int k4 = 0; k4 < K1 / 4; ++k4) {
                float4 xv = x4[k4];
                float4 w0 = sW4[(k4 * 4 + 0) * MG + lane];
                float4 w1 = sW4[(k4 * 4 + 1) * MG + lane];
                float4 w2 = sW4[(k4 * 4 + 2) * MG + lane];
                float4 w3 = sW4[(k4 * 4 + 3) * MG + lane];
                acc.x += xv.x * w0.x + xv.y * w1.x + xv.z * w2.x + xv.w * w3.x;
                acc.y += xv.x * w0.y + xv.y * w1.y + xv.z * w2.y + xv.w * w3.y;
                acc.z += xv.x * w0.z + xv.y * w1.z + xv.z * w2.z + xv.w * w3.z;
                acc.w += xv.x * w0.w + xv.y * w1.w + xv.z * w2.w + xv.w * w3.w;
            }
        }
        if (K2 > 0) {
            const float4* x4 = (const float4*)(X2 + n * K2);
#pragma unroll 4
            for (int k4 = 0; k4 < K2 / 4; ++k4) {
                float4 xv = x4[k4];
                float4 w0 = sW4[(K1 + k4 * 4 + 0) * MG + lane];
                float4 w1 = sW4[(K1 + k4 * 4 + 1) * MG + lane];
                float4 w2 = sW4[(K1 + k4 * 4 + 2) * MG + lane];
                float4 w3 = sW4[(K1 + k4 * 4 + 3) * MG + lane];
                acc.x += xv.x * w0.x + xv.y * w1.x + xv.z * w2.x + xv.w * w3.x;
                acc.y += xv.x * w0.y + xv.y * w1.y + xv.z * w2.y + xv.w * w3.y;
                acc.z += xv.x * w0.z + xv.y * w1.z + xv.z * w2.z + xv.w * w3.z;
                acc.w += xv.x * w0.w + xv.y * w1.w + xv.z * w2.w + xv.w * w3.w;
            }
        }
        if (rowscale) {
            float rs = rowscale[n];
            acc.x *= rs; acc.y *= rs; acc.z *= rs; acc.w *= rs;
        }
        if (bias) {
            float4 bv = *(const float4*)(bias + lane * 4);
            acc.x += bv.x; acc.y += bv.y; acc.z += bv.z; acc.w += bv.w;
        }
        if (ACT == 1) {
            acc.x = acc.x >= 0.f ? acc.x : 0.01f * acc.x;
            acc.y = acc.y >= 0.f ? acc.y : 0.01f * acc.y;
            acc.z = acc.z >= 0.f ? acc.z : 0.01f * acc.z;
            acc.w = acc.w >= 0.f ? acc.w : 0.01f * acc.w;
        } else if (ACT == 2) {
            acc.x = tanhf(acc.x); acc.y = tanhf(acc.y);
            acc.z = tanhf(acc.z); acc.w = tanhf(acc.w);
        } else if (ACT == 3) {
            acc.x = 1.f / (1.f + expf(-acc.x)); acc.y = 1.f / (1.f + expf(-acc.y));
            acc.z = 1.f / (1.f + expf(-acc.z)); acc.w = 1.f / (1.f + expf(-acc.w));
        }
        *(float4*)(Y + n * M + lane * 4) = acc;
    }
}

// ---------------- CSR build --------------------------------------------------
__global__ void count_int(const int* __restrict__ key, int* __restrict__ cnt, int E) {
    for (int e = blockIdx.x * blockDim.x + threadIdx.x; e < E; e += gridDim.x * blockDim.x)
        atomicAdd(&cnt[key[e]], 1);
}
__global__ void count_int2(const int* __restrict__ k1, const int* __restrict__ k2,
                           int* __restrict__ c1, int* __restrict__ c2, int E) {
    for (int e = blockIdx.x * blockDim.x + threadIdx.x; e < E; e += gridDim.x * blockDim.x) {
        atomicAdd(&c1[k1[e]], 1);
        atomicAdd(&c2[k2[e]], 1);
    }
}

// ---------------- device-wide 3-phase exclusive scan -------------------------
#define SCAN_T 256
#define SCAN_V 4
#define SCAN_CHUNK (SCAN_T * SCAN_V)

__global__ void scan_phase1(const int* __restrict__ cnt, int* __restrict__ out,
                            int* __restrict__ partials, int N) {
    __shared__ int sdata[SCAN_T];
    const int b = blockIdx.x;
    const int base = b * SCAN_CHUNK;
    int v[SCAN_V];
    int s = 0;
#pragma unroll
    for (int k = 0; k < SCAN_V; ++k) {
        int i = base + threadIdx.x * SCAN_V + k;
        v[k] = (i < N) ? cnt[i] : 0;
        s += v[k];
    }
    sdata[threadIdx.x] = s;
    __syncthreads();
    for (int ofs = 1; ofs < SCAN_T; ofs <<= 1) {
        int t = (threadIdx.x >= ofs) ? sdata[threadIdx.x - ofs] : 0;
        __syncthreads();
        sdata[threadIdx.x] += t;
        __syncthreads();
    }
    int excl = sdata[threadIdx.x] - s;
#pragma unroll
    for (int k = 0; k < SCAN_V; ++k) {
        int i = base + threadIdx.x * SCAN_V + k;
        if (i < N) out[i] = excl;
        excl += v[k];
    }
    if (threadIdx.x == SCAN_T - 1) partials[b] = sdata[SCAN_T - 1];
}

__global__ void scan_phase2(int* __restrict__ partials, int nb) {
    __shared__ int sdata[SCAN_T];
    int v = (threadIdx.x < nb) ? partials[threadIdx.x] : 0;
    sdata[threadIdx.x] = v;
    __syncthreads();
    for (int ofs = 1; ofs < SCAN_T; ofs <<= 1) {
        int t = (threadIdx.x >= ofs) ? sdata[threadIdx.x - ofs] : 0;
        __syncthreads();
        sdata[threadIdx.x] += t;
        __syncthreads();
    }
    if (threadIdx.x < nb) partials[threadIdx.x] = sdata[threadIdx.x] - v;
    if (threadIdx.x == SCAN_T - 1) partials[nb] = sdata[SCAN_T - 1];
}

__global__ void scan_phase3(int* __restrict__ rowptr, const int* __restrict__ partials,
                            int N, int nb) {
    int i = blockIdx.x * blockDim.x + threadIdx.x;
    if (i < N) rowptr[i] += partials[i / SCAN_CHUNK];
    else if (i == N) rowptr[N] = partials[nb];
}

// adj[pos] = val ? val[e] : e
__global__ void fill_adj(const int* __restrict__ key, const int* __restrict__ val,
                         int* __restrict__ cursor, int* __restrict__ adj, int E) {
    for (int e = blockIdx.x * blockDim.x + threadIdx.x; e < E; e += gridDim.x * blockDim.x) {
        int pos = atomicAdd(&cursor[key[e]], 1);
        adj[pos] = val ? val[e] : e;
    }
}

__global__ void deg_xform(const int* __restrict__ cnt, float* __restrict__ rs,
                          float* __restrict__ inv, int N) {
    for (int n = blockIdx.x * blockDim.x + threadIdx.x; n < N; n += gridDim.x * blockDim.x) {
        float d = fmaxf((float)cnt[n], 1.f);
        rs[n] = 1.f / sqrtf(d);
        if (inv) inv[n] = 1.f / d;
    }
}

// ---------------- GAT -------------------------------------------------------
__global__ void gat_scores(const float* __restrict__ h, const float* __restrict__ al,
                           const float* __restrict__ ar, float* __restrict__ el,
                           float* __restrict__ er, int N) {
    int idx = blockIdx.x * blockDim.x + threadIdx.x;
    if (idx >= N * 4) return;
    int n = idx >> 2, hd = idx & 3;
    const float* hp = h + (long long)n * 32 + hd * 8;
    float sl = 0.f, sr = 0.f;
#pragma unroll
    for (int f = 0; f < 8; ++f) {
        float v = hp[f];
        sl += v * al[hd * 8 + f];
        sr += v * ar[hd * 8 + f];
    }
    el[idx] = sl;
    er[idx] = sr;
}

// one thread per (dst,head): max pass, then fused exp/sum/weighted-accumulate
__global__ void gat_gather(const int* __restrict__ rowptr, const int* __restrict__ adjsrc,
                           const float* __restrict__ el, const float* __restrict__ er,
                           const float* __restrict__ gh, float* __restrict__ out,
                           int colOff, int N) {
    int idx = blockIdx.x * blockDim.x + threadIdx.x;
    if (idx >= N * 4) return;
    int d = idx >> 2, hd = idx & 3;
    int beg = rowptr[d], end = rowptr[d + 1];
    float rd = er[d * 4 + hd];
    float m = -1e30f;
    for (int p = beg; p < end; ++p) {
        float v = el[adjsrc[p] * 4 + hd] + rd;
        v = v >= 0.f ? v : 0.2f * v;
        m = fmaxf(m, v);
    }
    if (end == beg) m = 0.f;
    float sum = 0.f;
    float acc[8] = {0.f, 0.f, 0.f, 0.f, 0.f, 0.f, 0.f, 0.f};
    for (int p = beg; p < end; ++p) {
        int s = adjsrc[p];
        float v = el[s * 4 + hd] + rd;
        v = v >= 0.f ? v : 0.2f * v;
        float w = expf(v - m);
        sum += w;
        const float* hp = gh + (long long)s * 32 + hd * 8;
#pragma unroll
        for (int f = 0; f < 8; ++f) acc[f] += w * hp[f];
    }
    float inv = 1.f / fmaxf(sum, 1e-9f);
    float* op = out + (long long)d * 96 + hd * 16 + colOff;
#pragma unroll
    for (int f = 0; f < 8; ++f) op[f] = acc[f] * inv;
}

// ---------------- GraphConv gather (net <- sum over incoming pins) ----------
__global__ void gconv_gather(const int* __restrict__ rowptr, const int* __restrict__ adj,
                             const float* __restrict__ h, float* __restrict__ out, int N) {
    long long total = (long long)N * 32;
    long long stride = (long long)gridDim.x * blockDim.x;
    for (long long idx = (long long)blockIdx.x * blockDim.x + threadIdx.x; idx < total; idx += stride) {
        int n = (int)(idx >> 5), c = (int)(idx & 31);
        int beg = rowptr[n], end = rowptr[n + 1];
        float acc = 0.f;
        for (int p = beg; p < end; ++p) acc += h[(long long)adj[p] * 32 + c];
        out[idx] = acc;
    }
}

// ---------------- NNConv edge GEMM -> msg buffer -----------------------------
#define NN_TILE 64
__launch_bounds__(256, 2)
__global__ void nnconv_kernel(const int* __restrict__ esrc,   // net idx per edge (pins_dst)
                              const float* __restrict__ net,  // [Nnet,32]
                              const float* __restrict__ pinf, // [Ep,16]
                              const float* __restrict__ w,    // [16*1024]
                              const float* __restrict__ b2,   // [1024]
                              float* __restrict__ msg,        // [Ep,32]
                              int E) {
    __shared__ float sw[16 * 1024];
    __shared__ float sxT[32][NN_TILE];
    for (int t = threadIdx.x; t < 16 * 1024; t += 256) sw[t] = w[t];
    const float4* sw4 = (const float4*)sw;
    float4* msg4 = (float4*)msg;
    const int o4 = threadIdx.x & 7;
    const int eg = threadIdx.x >> 3;
    const int le0 = eg * 2;
    const int o0 = o4 * 4;
    const int ntiles = (E + NN_TILE - 1) / NN_TILE;
    for (int tile = blockIdx.x; tile < ntiles; tile += gridDim.x) {
        const int e0 = tile * NN_TILE;
        __syncthreads();
        for (int t = threadIdx.x; t < NN_TILE * 32; t += 256) {
            int le = t >> 5, c = t & 31;
            int e = e0 + le;
            sxT[c][le] = (e < E) ? net[(long long)esrc[e] * 32 + c] : 0.f;
        }
        float P0[16], P1[16];
        {
            int ea = e0 + le0, eb = e0 + le0 + 1;
#pragma unroll
            for (int k = 0; k < 16; ++k) {
                P0[k] = (ea < E) ? pinf[(long long)ea * 16 + k] : 0.f;
                P1[k] = (eb < E) ? pinf[(long long)eb * 16 + k] : 0.f;
            }
        }
        __syncthreads();
        float4 acc0 = {0.f, 0.f, 0.f, 0.f}, acc1 = {0.f, 0.f, 0.f, 0.f};
        for (int i = 0; i < 32; ++i) {
            float x0 = sxT[i][le0];
            float x1 = sxT[i][le0 + 1];
            float4 bv = *(const float4*)(b2 + i * 32 + o0);
            acc0.x += bv.x * x0; acc0.y += bv.y * x0; acc0.z += bv.z * x0; acc0.w += bv.w * x0;
            acc1.x += bv.x * x1; acc1.y += bv.y * x1; acc1.z += bv.z * x1; acc1.w += bv.w * x1;
#pragma unroll
            for (int k = 0; k < 16; ++k) {
                float4 wv = sw4[k * 256 + i * 8 + o4];
                float s0 = x0 * P0[k];
                float s1 = x1 * P1[k];
                acc0.x += wv.x * s0; acc0.y += wv.y * s0; acc0.z += wv.z * s0; acc0.w += wv.w * s0;
                acc1.x += wv.x * s1; acc1.y += wv.y * s1; acc1.z += wv.z * s1; acc1.w += wv.w * s1;
            }
        }
        int ea = e0 + le0;
        if (ea < E) msg4[(long long)ea * 8 + o4] = acc0;
        if (ea + 1 < E) msg4[(long long)(ea + 1) * 8 + o4] = acc1;
    }
}

// gather msg by node (pins_src CSR stores edge ids)
__global__ void nn_gather(const int* __restrict__ rowptr, const int* __restrict__ adjE,
                          const float* __restrict__ msg, float* __restrict__ out, int N) {
    long long total = (long long)N * 32;
    long long stride = (long long)gridDim.x * blockDim.x;
    for (long long idx = (long long)blockIdx.x * blockDim.x + threadIdx.x; idx < total; idx += stride) {
        int n = (int)(idx >> 5), o = (int)(idx & 31);
        int beg = rowptr[n], end = rowptr[n + 1];
        float acc = 0.f;
        for (int p = beg; p < end; ++p) acc += msg[(long long)adjE[p] * 32 + o];
        out[(long long)n * 96 + 64 + o] = acc;
    }
}

// ---------------- finalizers -------------------------------------------------
__global__ void finalize_node(float* __restrict__ node, const float* __restrict__ invN,
                              const float* __restrict__ gbias, const float* __restrict__ nnb, int N) {
    long long total = (long long)N * 96;
    long long stride = (long long)gridDim.x * blockDim.x;
    for (long long idx = (long long)blockIdx.x * blockDim.x + threadIdx.x; idx < total; idx += stride) {
        int n = (int)(idx / 96), c = (int)(idx % 96);
        float v = node[idx];
        if (c < 64) v += gbias[((c >> 4) << 3) | (c & 7)];
        else v = v * invN[n] + nnb[c - 64];
        node[idx] = tanhf(v);
    }
}
__global__ void finalize_net(float* __restrict__ net, const float* __restrict__ rsNet,
                             const float* __restrict__ gb, int N) {
    long long total = (long long)N * 32;
    long long stride = (long long)gridDim.x * blockDim.x;
    for (long long idx = (long long)blockIdx.x * blockDim.x + threadIdx.x; idx < total; idx += stride) {
        int n = (int)(idx >> 5), c = (int)(idx & 31);
        net[idx] = tanhf(net[idx] * rsNet[n] + gb[c]);
    }
}

// ---------------------------------------------------------------------------
extern "C" void kernel_launch(void* const* d_in, const int* in_sizes, int n_in,
                              void* d_out, int out_size, void* d_ws, size_t ws_size,
                              hipStream_t stream) {
    const float* in_node = (const float*)d_in[0];
    const float* in_net = (const float*)d_in[1];
    const float* in_pinf = (const float*)d_in[2];
    const float* node_lin_w = (const float*)d_in[3];
    const float* node_lin_b = (const float*)d_in[4];
    const float* net_lin_w = (const float*)d_in[5];
    const float* net_lin_b = (const float*)d_in[6];
    const float* pin_lin_w = (const float*)d_in[7];
    const float* pin_lin_b = (const float*)d_in[8];
    const float* gat_fc_w = (const float*)d_in[9];
    const float* gat_attn_l = (const float*)d_in[10];
    const float* gat_attn_r = (const float*)d_in[11];
    const float* gat_bias = (const float*)d_in[12];
    const float* gconv_w = (const float*)d_in[13];
    const float* gconv_b = (const float*)d_in[14];
    const float* lin2_w = (const float*)d_in[15];
    const float* lin2_b = (const float*)d_in[16];
    const float* nnconv_bias = (const float*)d_in[17];
    const float* out1_w = (const float*)d_in[18];
    const float* out1_b = (const float*)d_in[19];
    const float* out2_w = (const float*)d_in[20];
    const float* out2_b = (const float*)d_in[21];
    const float* out3_w = (const float*)d_in[22];
    const float* out3_b = (const float*)d_in[23];
    const int* pins_src = (const int*)d_in[24];
    const int* pins_dst = (const int*)d_in[25];
    const int* grid_src = (const int*)d_in[26];
    const int* grid_dst = (const int*)d_in[27];

    const int Nn = in_sizes[0] / 16;
    const int Nnet = in_sizes[1] / 8;
    const int Ep = in_sizes[2] / 8;
    const int Eg = in_sizes[26] / 2;

    char* base = (char*)d_ws;
    size_t off = 0;
    auto alloc = [&](size_t bytes) -> void* {
        void* p = base + off;
        off += (bytes + 255) & ~(size_t)255;
        return p;
    };
    float* pin = (float*)alloc((size_t)Ep * 16 * 4);
    float* msg = (float*)alloc((size_t)Ep * 32 * 4);
    float* rsN = (float*)alloc((size_t)Nn * 4);
    float* invN = (float*)alloc((size_t)Nn * 4);
    float* rsNet = (float*)alloc((size_t)Nnet * 4);
    int* cntN = (int*)alloc((size_t)Nn * 4);
    int* cntNet = (int*)alloc((size_t)Nnet * 4);
    int* cntG = (int*)alloc((size_t)Nn * 4);
    int* cursor = (int*)alloc((size_t)(Nn > Nnet ? Nn : Nnet) * 4);
    int* partials = (int*)alloc((size_t)260 * 4);
    float* nodeA = (float*)alloc((size_t)Nn * 96 * 4);
    float* nodeB = (float*)alloc((size_t)Nn * 96 * 4);
    float* netA = (float*)alloc((size_t)Nnet * 32 * 4);
    float* netB = (float*)alloc((size_t)Nnet * 32 * 4);
    float* gat_h = (float*)alloc((size_t)Nn * 32 * 4);
    float* el = (float*)alloc((size_t)Nn * 4 * 4);
    float* er = (float*)alloc((size_t)Nn * 4 * 4);
    float* gconv_h = (float*)alloc((size_t)Nn * 32 * 4);
    int* gridPtr0 = (int*)alloc((size_t)(Nn + 1) * 4);
    int* gridPtr1 = (int*)alloc((size_t)(Nn + 1) * 4);
    int* gridAdj0 = (int*)alloc((size_t)Eg * 4);
    int* gridAdj1 = (int*)alloc((size_t)Eg * 4);
    int* pinDstPtr = (int*)alloc((size_t)(Nnet + 1) * 4);
    int* pinDstAdj = (int*)alloc((size_t)Ep * 4);
    int* pinSrcPtr = (int*)alloc((size_t)(Nn + 1) * 4);
    int* pinSrcAdjE = (int*)alloc((size_t)Ep * 4);

    auto gsz = [](long long total) -> int {
        long long b = (total + 255) / 256;
        if (b < 1) b = 1;
        if (b > 4096) b = 4096;
        return (int)b;
    };

    // device-wide exclusive scan: cnt[N] -> rowptr[N+1]
    auto exscan = [&](const int* cnt, int* rowptr, int N) {
        int nb = (N + SCAN_CHUNK - 1) / SCAN_CHUNK;
        scan_phase1<<<nb, SCAN_T, 0, stream>>>(cnt, rowptr, partials, N);
        scan_phase2<<<1, SCAN_T, 0, stream>>>(partials, nb);
        scan_phase3<<<(N + 256) / 256 + 1, 256, 0, stream>>>(rowptr, partials, N, nb);
    };

    // ---- degrees for pins ----
    hipMemsetAsync(cntN, 0, (size_t)Nn * 4, stream);
    hipMemsetAsync(cntNet, 0, (size_t)Nnet * 4, stream);
    count_int2<<<gsz(Ep), 256, 0, stream>>>(pins_src, pins_dst, cntN, cntNet, Ep);
    deg_xform<<<gsz(Nn), 256, 0, stream>>>(cntN, rsN, invN, Nn);
    deg_xform<<<gsz(Nnet), 256, 0, stream>>>(cntNet, rsNet, nullptr, Nnet);

    // ---- CSR: pins by dst (net <- node), adj stores src node ----
    exscan(cntNet, pinDstPtr, Nnet);
    hipMemcpyAsync(cursor, pinDstPtr, (size_t)Nnet * 4, hipMemcpyDeviceToDevice, stream);
    fill_adj<<<gsz(Ep), 256, 0, stream>>>(pins_dst, pins_src, cursor, pinDstAdj, Ep);

    // ---- CSR: pins by src (node <- msg edges), adj stores edge id ----
    exscan(cntN, pinSrcPtr, Nn);
    hipMemcpyAsync(cursor, pinSrcPtr, (size_t)Nn * 4, hipMemcpyDeviceToDevice, stream);
    fill_adj<<<gsz(Ep), 256, 0, stream>>>(pins_src, nullptr, cursor, pinSrcAdjE, Ep);

    // ---- CSR: grid channels by dst, adj stores src node ----
    {
        int* ptrs[2] = {gridPtr0, gridPtr1};
        int* adjs[2] = {gridAdj0, gridAdj1};
        for (int j = 0; j < 2; ++j) {
            const int* gs = grid_src + (size_t)j * Eg;
            const int* gd = grid_dst + (size_t)j * Eg;
            hipMemsetAsync(cntG, 0, (size_t)Nn * 4, stream);
            count_int<<<gsz(Eg), 256, 0, stream>>>(gd, cntG, Eg);
            exscan(cntG, ptrs[j], Nn);
            hipMemcpyAsync(cursor, ptrs[j], (size_t)Nn * 4, hipMemcpyDeviceToDevice, stream);
            fill_adj<<<gsz(Eg), 256, 0, stream>>>(gd, gs, cursor, adjs[j], Eg);
        }
    }

    // tiled-GEMM launch helper: grid-stride, capped at 1280 blocks
    auto blocks_for = [](int N, int M) -> int {
        int rows = 256 / (M / 4);
        long long b = ((long long)N + rows - 1) / rows;
        if (b > 1280) b = 1280;
        return (int)b;
    };

    // ---- input transforms ----
    gemm_tiled<1, 16, 0, 96><<<blocks_for(Nn, 96), 256, 0, stream>>>(
        in_node, nullptr, nullptr, node_lin_w, node_lin_b, nodeA, Nn);
    gemm_tiled<1, 8, 0, 32><<<blocks_for(Nnet, 32), 256, 0, stream>>>(
        in_net, nullptr, nullptr, net_lin_w, net_lin_b, netA, Nnet);
    gemm_tiled<1, 8, 0, 16><<<blocks_for(Ep, 16), 256, 0, stream>>>(
        in_pinf, nullptr, nullptr, pin_lin_w, pin_lin_b, pin, Ep);

    float* node_cur = nodeA; float* node_nxt = nodeB;
    float* net_cur = netA;  float* net_nxt = netB;

    for (int i = 0; i < 2; ++i) {
        // GAT shared projection + attention scores
        gemm_tiled<0, 96, 0, 32><<<blocks_for(Nn, 32), 256, 0, stream>>>(
            node_cur, nullptr, nullptr, gat_fc_w + (size_t)i * 96 * 32, nullptr, gat_h, Nn);
        gat_scores<<<(Nn * 4 + 255) / 256, 256, 0, stream>>>(
            gat_h, gat_attn_l + i * 32, gat_attn_r + i * 32, el, er, Nn);

        gat_gather<<<(Nn * 4 + 255) / 256, 256, 0, stream>>>(
            gridPtr0, gridAdj0, el, er, gat_h, node_nxt, 0, Nn);
        gat_gather<<<(Nn * 4 + 255) / 256, 256, 0, stream>>>(
            gridPtr1, gridAdj1, el, er, gat_h, node_nxt, 8, Nn);

        // GraphConv: h = (node * deg^-1/2) @ W; gather to nets
        gemm_tiled<0, 96, 0, 32><<<blocks_for(Nn, 32), 256, 0, stream>>>(
            node_cur, nullptr, rsN, gconv_w + (size_t)i * 96 * 32, nullptr, gconv_h, Nn);
        gconv_gather<<<gsz((long long)Nnet * 32), 256, 0, stream>>>(
            pinDstPtr, pinDstAdj, gconv_h, net_nxt, Nnet);

        // NNConv: per-edge weight matrices -> msg, then gather by node
        {
            int ntiles = (Ep + NN_TILE - 1) / NN_TILE;
            int g = ntiles < 512 ? ntiles : 512;
            nnconv_kernel<<<g, 256, 0, stream>>>(pins_dst, net_cur, pin,
                                                 lin2_w + (size_t)i * 16 * 1024,
                                                 lin2_b + (size_t)i * 1024, msg, Ep);
        }
        nn_gather<<<gsz((long long)Nn * 32), 256, 0, stream>>>(
            pinSrcPtr, pinSrcAdjE, msg, node_nxt, Nn);

        finalize_node<<<gsz((long long)Nn * 96), 256, 0, stream>>>(
            node_nxt, invN, gat_bias + i * 32, nnconv_bias + i * 32, Nn);
        finalize_net<<<gsz((long long)Nnet * 32), 256, 0, stream>>>(net_nxt, rsNet, gconv_b + i * 32, Nnet);

        float* t = node_cur; node_cur = node_nxt; node_nxt = t;
        t = net_cur; net_cur = net_nxt; net_nxt = t;
    }

    // output MLP
    float* h1 = node_nxt;
    gemm_tiled<2, 16, 96, 96><<<blocks_for(Nn, 96), 256, 0, stream>>>(
        in_node, node_cur, nullptr, out1_w, out1_b, h1, Nn);
    float* h2 = node_cur;
    gemm_tiled<2, 96, 0, 96><<<blocks_for(Nn, 96), 256, 0, stream>>>(
        h1, nullptr, nullptr, out2_w, out2_b, h2, Nn);
    gemm_tiled<3, 96, 0, 4><<<blocks_for(Nn, 4), 256, 0, stream>>>(
        h2, nullptr, nullptr, out3_w, out3_b, (float*)d_out, Nn);
}